// Round 7
// baseline (159.701 us; speedup 1.0000x reference)
//
#include <hip/hip_runtime.h>
#include <hip/hip_cooperative_groups.h>

// S1Net fused: one cooperative kernel. I = round(input_n*20) ∈ {0..20} -> the
// 200-step Izhikevich sim is a per-block 21-entry LUT (r4/r6 A/B: in-kernel vs
// separate kernel neutral). fired_any = grid-wide OR via per-block flags +
// grid.sync() + per-block L2 re-reduce; W_LatInh phase keeps input_n/WLi in
// registers across the sync. Removes memset+kLUT+kB nodes (graph-gap + serial
// kLUT + 4MB re-read). All numerics copied VERBATIM from the r4/r6 passing
// kernels (non-contracted chains, XLA tanh coefficients, RNE rounding).

namespace cg = cooperative_groups;

namespace {

constexpr int N    = 500000;
constexpr int NT4  = N / 4;                    // 125000 threads, 4 neurons each
constexpr int BLK  = 256;
constexpr int NBLK = (NT4 + BLK - 1) / BLK;    // 489

// XLA/Eigen f32 tanh rational approximation, non-contracted (threshold-safe).
__device__ __forceinline__ float xla_tanh(float x) {
  float xc = fminf(fmaxf(x, -9.0f), 9.0f);
  float x2 = __fmul_rn(xc, xc);
  float p = -2.76076847742355e-16f;
  p = __fadd_rn(__fmul_rn(p, x2), 2.00018790482477e-13f);
  p = __fadd_rn(__fmul_rn(p, x2), -8.60467152213735e-11f);
  p = __fadd_rn(__fmul_rn(p, x2), 5.12229709037114e-08f);
  p = __fadd_rn(__fmul_rn(p, x2), 1.48572235717979e-05f);
  p = __fadd_rn(__fmul_rn(p, x2), 6.37261928875436e-04f);
  p = __fadd_rn(__fmul_rn(p, x2), 4.89352455891786e-03f);
  p = __fmul_rn(xc, p);
  float q = 1.19825839466702e-06f;
  q = __fadd_rn(__fmul_rn(q, x2), 1.18534705686654e-04f);
  q = __fadd_rn(__fmul_rn(q, x2), 2.26843463243900e-03f);
  q = __fadd_rn(__fmul_rn(q, x2), 4.89352518554385e-03f);
  float r = p / q;
  return (fabsf(x) < 0.0004f) ? x : r;
}

__global__ void __launch_bounds__(BLK) kFused(const float* __restrict__ inp,
                                              const float* __restrict__ FR,
                                              const float* __restrict__ C,
                                              const float* __restrict__ W,
                                              const float* __restrict__ WLi,
                                              const float* __restrict__ Fired,
                                              float* __restrict__ out,
                                              unsigned int* __restrict__ flags) {
  __shared__ float lut[24];
  __shared__ unsigned int s_or;
  const int tid = threadIdx.x;
  const int bid = blockIdx.x;
  const int gid = bid * BLK + tid;
  const bool active = gid < NT4;
  const int src = active ? gid : 0;          // clamp so tail threads load safely

  if (tid == 0) s_or = 0u;

  // Issue all global loads up front (WLi too — lives in registers to phase 2).
  float4 in4 = reinterpret_cast<const float4*>(inp)[src];
  float4 c4  = reinterpret_cast<const float4*>(C)[src];
  float4 wl4 = reinterpret_cast<const float4*>(WLi)[src];
  float fa[8][4], wa[8][4];
#pragma unroll
  for (int k = 0; k < 8; ++k) {
    float4 fv = reinterpret_cast<const float4*>(FR + (size_t)k * N)[src];
    float4 wv = reinterpret_cast<const float4*>(W + (size_t)k * N)[src];
    fa[k][0] = fv.x; fa[k][1] = fv.y; fa[k][2] = fv.z; fa[k][3] = fv.w;
    wa[k][0] = wv.x; wa[k][1] = wv.y; wa[k][2] = wv.z; wa[k][3] = wv.w;
  }

  // 21 Izhikevich sims (I = 0..20) on lanes 0..20 of wave 0 — VERBATIM from
  // the passing kernel; latency overlaps the HBM loads across resident blocks.
  if (tid < 21) {
    const float I = (float)tid;
    float mem = -70.0f, u = -14.0f, acc = 0.0f;
#pragma unroll 10
    for (int t = 0; t < 200; ++t) {
      float dm = (0.04f * mem) * mem + 5.0f * mem;  // reference assoc order
      dm = dm + 140.0f;
      dm = dm - u;
      dm = dm + I;
      mem = mem + 0.5f * dm;                 // DT = 0.5
      u = u + 0.01f * (0.2f * mem - u);      // DT*A = 0.01, uses NEW mem
      const bool sp = mem >= 30.0f;
      acc += sp ? 1.0f : 0.0f;
      mem = sp ? -65.0f : mem;               // C_RESET
      u = sp ? u + 8.0f : u;                 // D
    }
    lut[tid] = acc / 200.0f;                 // FR_n for this I
  }
  __syncthreads();                            // guards lut[] and s_or init

  float in_n[4];
  bool s_any = false;
  if (active) {
    // FR_W dot product: sequential add order, no contraction (threshold-safe).
    float frw[4];
#pragma unroll
    for (int j = 0; j < 4; ++j) {
      float s = __fmul_rn(fa[0][j], wa[0][j]);
#pragma unroll
      for (int k = 1; k < 8; ++k)
        s = __fadd_rn(s, __fmul_rn(fa[k][j], wa[k][j]));
      frw[j] = s;
    }
    const float iv[4] = {in4.x, in4.y, in4.z, in4.w};
    const float cv[4] = {c4.x, c4.y, c4.z, c4.w};
    float fr_n[4];
#pragma unroll
    for (int j = 0; j < 4; ++j) {
      float sf = fmaxf(xla_tanh(frw[j]), 0.0f);
      float d  = __fsub_rn(iv[j], sf);
      float v  = __fadd_rn(__fmul_rn(-cv[j], d), iv[j]);  // -C*(input-sf)+input
      float n  = fmaxf(v, 0.0f);
      in_n[j] = n;
      int ir = (int)rintf(__fmul_rn(n, 20.0f));           // RNE == jnp.round
      ir = ir < 0 ? 0 : (ir > 20 ? 20 : ir);
      fr_n[j] = lut[ir];
      s_any |= (n >= 0.5f);
    }
    float4 o0 = {fr_n[0], fr_n[1], fr_n[2], fr_n[3]};
    float4 o1 = {in_n[0], in_n[1], in_n[2], in_n[3]};
    reinterpret_cast<float4*>(out)[gid] = o0;           // FR_n
    reinterpret_cast<float4*>(out + N)[gid] = o1;       // input_n
  }

  // Per-block fired flag (no init needed: written before anyone reads it).
  unsigned long long b = __ballot(s_any);
  if ((tid & 63) == 0 && b != 0ULL) s_or = 1u;   // per-wave, benign race
  __syncthreads();
  if (tid == 0) flags[bid] = s_or;

  cg::this_grid().sync();                         // flags now globally visible

  // Grid OR: each block re-reduces all 489 flags (L2-resident, ~2 loads/thread).
  unsigned int v = 0;
  for (int i = tid; i < NBLK; i += BLK) v |= flags[i];
  if (tid == 0) s_or = 0u;
  __syncthreads();
  if (v != 0u) s_or = 1u;                         // benign race
  __syncthreads();

  const float fired_any = s_or ? 1.0f : 0.0f;
  const float fired_new = __fadd_rn(Fired[0], fired_any);
  if (gid == 0) out[2 * N] = fired_new;

  if (active) {
    const float wv[4] = {wl4.x, wl4.y, wl4.z, wl4.w};
    float res[4];
    if (fired_any > 0.0f) {
      const float e = expf(fired_new);
#pragma unroll
      for (int j = 0; j < 4; ++j) {
        // 2*arccos(S): S=1 -> 0, S=0 -> pi (f32); S=0 path saturates tanh clamp
        float two_acos = (in_n[j] >= 0.5f) ? 0.0f : 3.14159274101257324f;
        float t = __fmul_rn(two_acos, e);
        float x = __fsub_rn(wv[j], t);
        x = __fsub_rn(x, 1.0f);
        res[j] = __fadd_rn(xla_tanh(x), 1.0f);
      }
    } else {
#pragma unroll
      for (int j = 0; j < 4; ++j) res[j] = wv[j];
    }
    float* dst = out + 2 * N + 1 + (size_t)gid * 4;  // odd base: scalar stores
    dst[0] = res[0]; dst[1] = res[1]; dst[2] = res[2]; dst[3] = res[3];
  }
}

}  // namespace

extern "C" void kernel_launch(void* const* d_in, const int* in_sizes, int n_in,
                              void* d_out, int out_size, void* d_ws, size_t ws_size,
                              hipStream_t stream) {
  const float* inp   = (const float*)d_in[0];
  const float* FR    = (const float*)d_in[1];
  const float* C     = (const float*)d_in[2];
  const float* Fired = (const float*)d_in[3];
  const float* WLi   = (const float*)d_in[4];
  const float* W     = (const float*)d_in[5];
  float* out = (float*)d_out;
  unsigned int* flags = (unsigned int*)d_ws;   // NBLK uints, written before read

  void* args[] = {(void*)&inp, (void*)&FR, (void*)&C, (void*)&W,
                  (void*)&WLi, (void*)&Fired, (void*)&out, (void*)&flags};
  hipLaunchCooperativeKernel((const void*)kFused, dim3(NBLK), dim3(BLK),
                             args, 0, stream);
}

// Round 11
// 98.075 us; speedup vs baseline: 1.6284x; 1.6284x over previous
//
#include <hip/hip_runtime.h>

// S1Net, 2-kernel chain (r7 cooperative fusion regressed 52.9us vs ~12us — reverted).
// kA: stream inp/C/FR/W -> FR_n, input_n; 200-step Izhikevich sim folded to a
//     21-entry LUT (I=round(input_n*20) in {0..20}; in-kernel sim proven neutral
//     r4 vs r6). S bits packed as per-wave ballots into ws; per-block fired flag.
// kB: OR 489 flags -> fired_any; WLi + ballot bits -> W_LatInh_new. No memset
//     node: everything in ws is written before it is read.
// Numerics verbatim from the r4/r6 passing kernels (non-contracted chains, XLA
// tanh coefficients, RNE rounding); S bit in kB comes from kA's own compare.
// Resubmission: r8/r9/r10 broker timeouts, kernel never ran.

namespace {

constexpr int N    = 500000;
constexpr int NT4  = N / 4;                    // 125000 threads, 4 neurons each
constexpr int BLK  = 256;
constexpr int NBLK = (NT4 + BLK - 1) / BLK;    // 489

// XLA/Eigen f32 tanh rational approximation, non-contracted (threshold-safe).
__device__ __forceinline__ float xla_tanh(float x) {
  float xc = fminf(fmaxf(x, -9.0f), 9.0f);
  float x2 = __fmul_rn(xc, xc);
  float p = -2.76076847742355e-16f;
  p = __fadd_rn(__fmul_rn(p, x2), 2.00018790482477e-13f);
  p = __fadd_rn(__fmul_rn(p, x2), -8.60467152213735e-11f);
  p = __fadd_rn(__fmul_rn(p, x2), 5.12229709037114e-08f);
  p = __fadd_rn(__fmul_rn(p, x2), 1.48572235717979e-05f);
  p = __fadd_rn(__fmul_rn(p, x2), 6.37261928875436e-04f);
  p = __fadd_rn(__fmul_rn(p, x2), 4.89352455891786e-03f);
  p = __fmul_rn(xc, p);
  float q = 1.19825839466702e-06f;
  q = __fadd_rn(__fmul_rn(q, x2), 1.18534705686654e-04f);
  q = __fadd_rn(__fmul_rn(q, x2), 2.26843463243900e-03f);
  q = __fadd_rn(__fmul_rn(q, x2), 4.89352518554385e-03f);
  float r = p / q;
  return (fabsf(x) < 0.0004f) ? x : r;
}

__global__ void __launch_bounds__(BLK) kA(const float* __restrict__ inp,
                                          const float* __restrict__ FR,
                                          const float* __restrict__ C,
                                          const float* __restrict__ W,
                                          float* __restrict__ out,
                                          unsigned int* __restrict__ flags,
                                          unsigned long long* __restrict__ ballots) {
  __shared__ float lut[24];
  __shared__ unsigned int s_or;
  const int tid = threadIdx.x;
  const int bid = blockIdx.x;
  const int gid = bid * BLK + tid;
  const bool active = gid < NT4;
  const int src = active ? gid : 0;          // clamp so tail threads load safely

  if (tid == 0) s_or = 0u;

  // Issue all global loads up front so they're in flight during the sim.
  float4 in4 = reinterpret_cast<const float4*>(inp)[src];
  float4 c4  = reinterpret_cast<const float4*>(C)[src];
  float fa[8][4], wa[8][4];
#pragma unroll
  for (int k = 0; k < 8; ++k) {
    float4 fv = reinterpret_cast<const float4*>(FR + (size_t)k * N)[src];
    float4 wv = reinterpret_cast<const float4*>(W + (size_t)k * N)[src];
    fa[k][0] = fv.x; fa[k][1] = fv.y; fa[k][2] = fv.z; fa[k][3] = fv.w;
    wa[k][0] = wv.x; wa[k][1] = wv.y; wa[k][2] = wv.z; wa[k][3] = wv.w;
  }

  // 21 Izhikevich sims (I = 0..20) on lanes 0..20 of wave 0 — VERBATIM from
  // the passing kernels; chain latency overlaps loads across resident blocks.
  if (tid < 21) {
    const float I = (float)tid;
    float mem = -70.0f, u = -14.0f, acc = 0.0f;
#pragma unroll 10
    for (int t = 0; t < 200; ++t) {
      float dm = (0.04f * mem) * mem + 5.0f * mem;  // reference assoc order
      dm = dm + 140.0f;
      dm = dm - u;
      dm = dm + I;
      mem = mem + 0.5f * dm;                 // DT = 0.5
      u = u + 0.01f * (0.2f * mem - u);      // DT*A = 0.01, uses NEW mem
      const bool sp = mem >= 30.0f;
      acc += sp ? 1.0f : 0.0f;
      mem = sp ? -65.0f : mem;               // C_RESET
      u = sp ? u + 8.0f : u;                 // D
    }
    lut[tid] = acc / 200.0f;                 // FR_n for this I
  }
  __syncthreads();                            // guards lut[] and s_or init

  float in_n[4] = {0.f, 0.f, 0.f, 0.f};
  if (active) {
    // FR_W dot product: sequential add order, no contraction (threshold-safe).
    float frw[4];
#pragma unroll
    for (int j = 0; j < 4; ++j) {
      float s = __fmul_rn(fa[0][j], wa[0][j]);
#pragma unroll
      for (int k = 1; k < 8; ++k)
        s = __fadd_rn(s, __fmul_rn(fa[k][j], wa[k][j]));
      frw[j] = s;
    }
    const float iv[4] = {in4.x, in4.y, in4.z, in4.w};
    const float cv[4] = {c4.x, c4.y, c4.z, c4.w};
    float fr_n[4];
#pragma unroll
    for (int j = 0; j < 4; ++j) {
      float sf = fmaxf(xla_tanh(frw[j]), 0.0f);
      float d  = __fsub_rn(iv[j], sf);
      float v  = __fadd_rn(__fmul_rn(-cv[j], d), iv[j]);  // -C*(input-sf)+input
      float n  = fmaxf(v, 0.0f);
      in_n[j] = n;
      int ir = (int)rintf(__fmul_rn(n, 20.0f));           // RNE == jnp.round
      ir = ir < 0 ? 0 : (ir > 20 ? 20 : ir);
      fr_n[j] = lut[ir];
    }
    float4 o0 = {fr_n[0], fr_n[1], fr_n[2], fr_n[3]};
    float4 o1 = {in_n[0], in_n[1], in_n[2], in_n[3]};
    reinterpret_cast<float4*>(out)[gid] = o0;           // FR_n
    reinterpret_cast<float4*>(out + N)[gid] = o1;       // input_n
  }

  // Pack S bits: 4 ballots per wave (one per neuron slot j). Inactive lanes
  // contribute 0. kB re-reads these instead of the 2MB input_n array.
  const int gw = gid >> 6;                    // global wave id (grid-uniform map)
  bool any = false;
#pragma unroll
  for (int j = 0; j < 4; ++j) {
    unsigned long long b = __ballot(active && (in_n[j] >= 0.5f));
    any |= (b != 0ULL);
    if ((tid & 63) == 0) ballots[gw * 4 + j] = b;
  }
  if ((tid & 63) == 0 && any) s_or = 1u;      // benign same-value race
  __syncthreads();
  if (tid == 0) flags[bid] = s_or;
}

__global__ void __launch_bounds__(BLK) kB(const float* __restrict__ WLi,
                                          const float* __restrict__ Fired,
                                          const unsigned int* __restrict__ flags,
                                          const unsigned long long* __restrict__ ballots,
                                          float* __restrict__ out) {
  __shared__ unsigned int s_or;
  const int tid = threadIdx.x;
  const int gid = blockIdx.x * BLK + tid;
  if (tid == 0) s_or = 0u;
  __syncthreads();
  unsigned int v = 0;
  for (int i = tid; i < NBLK; i += BLK) v |= flags[i];  // 489 words, L2-hit
  if (v != 0u) s_or = 1u;                               // benign race
  __syncthreads();

  const float fired_any = s_or ? 1.0f : 0.0f;
  const float fired_new = __fadd_rn(Fired[0], fired_any);
  if (gid == 0) out[2 * N] = fired_new;
  if (gid >= NT4) return;

  float4 wl4 = reinterpret_cast<const float4*>(WLi)[gid];
  const float wv[4] = {wl4.x, wl4.y, wl4.z, wl4.w};
  const int gw = gid >> 6;
  const int lane = gid & 63;
  float res[4];

  if (fired_any > 0.0f) {
    const float e = expf(fired_new);
#pragma unroll
    for (int j = 0; j < 4; ++j) {
      // S bit from kA's own compare; 2*arccos(S): S=1 -> 0, S=0 -> pi (f32).
      // S=0 drives tanh into its clamp, so exp ULP noise cannot surface.
      const bool S = (ballots[gw * 4 + j] >> lane) & 1ULL;  // broadcast load
      float two_acos = S ? 0.0f : 3.14159274101257324f;
      float t = __fmul_rn(two_acos, e);
      float x = __fsub_rn(wv[j], t);
      x = __fsub_rn(x, 1.0f);
      res[j] = __fadd_rn(xla_tanh(x), 1.0f);
    }
  } else {
#pragma unroll
    for (int j = 0; j < 4; ++j) res[j] = wv[j];
  }

  float* dst = out + 2 * N + 1 + (size_t)gid * 4;  // odd base: scalar stores (2MB)
  dst[0] = res[0]; dst[1] = res[1]; dst[2] = res[2]; dst[3] = res[3];
}

}  // namespace

extern "C" void kernel_launch(void* const* d_in, const int* in_sizes, int n_in,
                              void* d_out, int out_size, void* d_ws, size_t ws_size,
                              hipStream_t stream) {
  const float* inp   = (const float*)d_in[0];
  const float* FR    = (const float*)d_in[1];
  const float* C     = (const float*)d_in[2];
  const float* Fired = (const float*)d_in[3];
  const float* WLi   = (const float*)d_in[4];
  const float* W     = (const float*)d_in[5];
  float* out = (float*)d_out;

  // ws layout (all written by kA before kB reads; poison harmless, no memset):
  unsigned int* flags = (unsigned int*)d_ws;                       // 489 words
  unsigned long long* ballots =
      (unsigned long long*)((char*)d_ws + 4096);                   // 4*1956 words

  kA<<<NBLK, BLK, 0, stream>>>(inp, FR, C, W, out, flags, ballots);
  kB<<<NBLK, BLK, 0, stream>>>(WLi, Fired, flags, ballots, out);
}